// Round 2
// baseline (1183.990 us; speedup 1.0000x reference)
//
#include <hip/hip_runtime.h>

// Problem constants (fixed by reference setup_inputs)
constexpr int T_DIM = 10, C_DIM = 3, H_DIM = 512, W_DIM = 512;
constexpr int PT = 2, PS = 7;
constexpr int ELEM_PER_Q = PT * C_DIM * PS * PS;  // 294
constexpr int HALF      = C_DIM * PS * PS;        // 147 (one dt-slice of a patch)
constexpr int TILE = 76;                           // exclusive output tile (h,w)
constexpr int NBH = 7, NBW = 7;                    // anchor bins: h,w in [0,505] -> /76 -> 0..6
constexpr int NTB = T_DIM - PT + 1;                // 9 anchor t values
constexpr int NBINS = NTB * NBH * NBW;             // 441

// d_ws layout (ints): counts[512] | offsets[512] | cursors[512] | list[Q]

__global__ __launch_bounds__(256) void ScatterNL_hist(
    const int* __restrict__ qinds, int Q, int* __restrict__ counts)
{
    __shared__ int hloc[NBINS];
    for (int i = threadIdx.x; i < NBINS; i += blockDim.x) hloc[i] = 0;
    __syncthreads();
    int stride = gridDim.x * blockDim.x;
    for (int q = blockIdx.x * blockDim.x + threadIdx.x; q < Q; q += stride) {
        int t = qinds[3*q], h = qinds[3*q+1], w = qinds[3*q+2];
        int b = (t * NBH + h / TILE) * NBW + w / TILE;
        atomicAdd(&hloc[b], 1);
    }
    __syncthreads();
    for (int i = threadIdx.x; i < NBINS; i += blockDim.x)
        if (hloc[i]) atomicAdd(&counts[i], hloc[i]);
}

__global__ __launch_bounds__(512) void ScatterNL_scan(
    const int* __restrict__ counts, int* __restrict__ offsets,
    int* __restrict__ cursors)
{
    __shared__ int buf[2][512];
    int tid = threadIdx.x;
    buf[0][tid] = (tid < NBINS) ? counts[tid] : 0;
    __syncthreads();
    int src = 0;
    for (int d = 1; d < 512; d <<= 1) {
        int x = buf[src][tid] + ((tid >= d) ? buf[src][tid - d] : 0);
        buf[src ^ 1][tid] = x;
        __syncthreads();
        src ^= 1;
    }
    int excl = (tid == 0) ? 0 : buf[src][tid - 1];
    if (tid < NBINS) {
        offsets[tid] = excl;
        cursors[tid] = excl;
    }
    if (tid == NBINS) offsets[NBINS] = buf[src][NBINS - 1];
}

__global__ __launch_bounds__(256) void ScatterNL_fill(
    const int* __restrict__ qinds, int Q, int* __restrict__ cursors,
    int* __restrict__ list)
{
    int stride = gridDim.x * blockDim.x;
    for (int q = blockIdx.x * blockDim.x + threadIdx.x; q < Q; q += stride) {
        int t = qinds[3*q], h = qinds[3*q+1], w = qinds[3*q+2];
        int b = (t * NBH + h / TILE) * NBW + w / TILE;
        int pos = atomicAdd(&cursors[b], 1);
        list[pos] = q;
    }
}

__global__ __launch_bounds__(512) void ScatterNL_accum(
    const float* __restrict__ vid, const float* __restrict__ patches,
    const int* __restrict__ qinds, const int* __restrict__ offsets,
    const int* __restrict__ list, float* __restrict__ out)
{
    __shared__ float acc[C_DIM * TILE * TILE];   // 69,312 B -> 2 blocks/CU

    int bid = blockIdx.x;
    int ts  = bid / (NBH * NBW);                 // output t-slice 0..9
    int r   = bid % (NBH * NBW);
    int bh  = r / NBW, bw = r % NBW;
    int h0  = bh * TILE, w0 = bw * TILE;
    int THe = min(TILE, H_DIM - h0);             // 76 (or 56 on last row)
    int TWe = min(TILE, W_DIM - w0);

    for (int i = threadIdx.x; i < C_DIM * TILE * TILE; i += blockDim.x)
        acc[i] = 0.f;
    __syncthreads();

    const int lane = threadIdx.x & 63;
    const int wv   = threadIdx.x >> 6;           // 0..7
    const int NW   = blockDim.x >> 6;            // 8 waves

    // Per-lane (c,i,j) for k = lane, lane+64, lane+128 — fixed for all queries.
    int cc[3], ii[3], jj[3]; bool vld[3];
    #pragma unroll
    for (int s = 0; s < 3; ++s) {
        int k = lane + 64 * s;
        vld[s] = (k < HALF);
        int kk = vld[s] ? k : 0;
        cc[s] = kk / 49;
        int rr = kk % 49;
        ii[s] = rr / 7;
        jj[s] = rr % 7;
    }

    for (int tb = ts - 1; tb <= ts; ++tb) {
        if (tb < 0 || tb > T_DIM - PT) continue;
        int dt = ts - tb;                        // which half of the patch lands here
        for (int sh = bh - 1; sh <= bh; ++sh) {
            if (sh < 0) continue;
            for (int sw = bw - 1; sw <= bw; ++sw) {
                if (sw < 0) continue;
                int bin   = (tb * NBH + sh) * NBW + sw;
                int start = offsets[bin], end = offsets[bin + 1];
                for (int qi = start + wv; qi < end; qi += NW) {
                    int q  = list[qi];
                    int qh = qinds[3*q+1], qw = qinds[3*q+2];
                    // wave-uniform tile-intersection test
                    if (qh + PS <= h0 || qh >= h0 + THe ||
                        qw + PS <= w0 || qw >= w0 + TWe) continue;
                    const float* base = patches + (size_t)q * ELEM_PER_Q + dt * HALF;
                    float v0 = vld[0] ? base[lane]       : 0.f;
                    float v1 = vld[1] ? base[lane + 64]  : 0.f;
                    float v2 = vld[2] ? base[lane + 128] : 0.f;
                    #pragma unroll
                    for (int s = 0; s < 3; ++s) {
                        if (!vld[s]) continue;
                        float v = (s == 0) ? v0 : (s == 1) ? v1 : v2;
                        int hh = qh + ii[s] - h0;
                        int ww = qw + jj[s] - w0;
                        if (hh >= 0 && hh < THe && ww >= 0 && ww < TWe)
                            atomicAdd(&acc[(cc[s] * TILE + hh) * TILE + ww], v);
                    }
                }
            }
        }
    }
    __syncthreads();

    // Exclusive write-out: out = vid2fill + acc. Each output element written once.
    for (int row = wv; row < C_DIM * THe; row += NW) {
        int c = row / THe, y = row % THe;
        size_t obase = (((size_t)ts * C_DIM + c) * H_DIM + (h0 + y)) * W_DIM + w0;
        const float* lrow = &acc[(c * TILE + y) * TILE];
        for (int x = lane; x < TWe; x += 64)
            out[obase + x] = vid[obase + x] + lrow[x];
    }
}

extern "C" void kernel_launch(void* const* d_in, const int* in_sizes, int n_in,
                              void* d_out, int out_size, void* d_ws, size_t ws_size,
                              hipStream_t stream) {
    const float* vid     = (const float*)d_in[0];
    const float* patches = (const float*)d_in[1];
    const int*   qinds   = (const int*)d_in[2];
    float* out = (float*)d_out;
    int Q = in_sizes[2] / 3;

    int* ws      = (int*)d_ws;
    int* counts  = ws;
    int* offsets = ws + 512;
    int* cursors = ws + 1024;
    int* list    = ws + 1536;

    hipMemsetAsync(counts, 0, 512 * sizeof(int), stream);  // ws is poisoned each call
    ScatterNL_hist<<<256, 256, 0, stream>>>(qinds, Q, counts);
    ScatterNL_scan<<<1, 512, 0, stream>>>(counts, offsets, cursors);
    ScatterNL_fill<<<256, 256, 0, stream>>>(qinds, Q, cursors, list);
    ScatterNL_accum<<<T_DIM * NBH * NBW, 512, 0, stream>>>(
        vid, patches, qinds, offsets, list, out);
}

// Round 3
// 881.106 us; speedup vs baseline: 1.3438x; 1.3438x over previous
//
#include <hip/hip_runtime.h>

// Problem constants (fixed by reference setup_inputs)
constexpr int T_DIM = 10, C_DIM = 3, H_DIM = 512, W_DIM = 512;
constexpr int PT = 2, PS = 7;
constexpr int ELEM_PER_Q = PT * C_DIM * PS * PS;  // 294
constexpr int HALF      = C_DIM * PS * PS;        // 147 (one dt-slice of a patch)
constexpr int TILE = 38;                           // exclusive output tile (h,w)
constexpr int NBH = 14, NBW = 14;                  // anchor bins: ceil(506/38)=14; tiles: ceil(512/38)=14
constexpr int NTB = T_DIM - PT + 1;                // 9 anchor t values
constexpr int NBINS = NTB * NBH * NBW;             // 1764
constexpr int BINPAD = 2048;

// d_ws layout (ints): counts[2048] | offsets[2048] | cursors[2048] | list[Q]

__global__ __launch_bounds__(256) void ScatterNL_hist(
    const int* __restrict__ qinds, int Q, int* __restrict__ counts)
{
    __shared__ int hloc[NBINS];
    for (int i = threadIdx.x; i < NBINS; i += blockDim.x) hloc[i] = 0;
    __syncthreads();
    int stride = gridDim.x * blockDim.x;
    for (int q = blockIdx.x * blockDim.x + threadIdx.x; q < Q; q += stride) {
        int t = qinds[3*q], h = qinds[3*q+1], w = qinds[3*q+2];
        int b = (t * NBH + h / TILE) * NBW + w / TILE;
        atomicAdd(&hloc[b], 1);
    }
    __syncthreads();
    for (int i = threadIdx.x; i < NBINS; i += blockDim.x)
        if (hloc[i]) atomicAdd(&counts[i], hloc[i]);
}

// 256 threads, each owns 7 consecutive bins (256*7=1792 >= 1764).
__global__ __launch_bounds__(256) void ScatterNL_scan(
    const int* __restrict__ counts, int* __restrict__ offsets,
    int* __restrict__ cursors)
{
    __shared__ int buf[2][256];
    int tid = threadIdx.x;
    int base = tid * 7;
    int loc[7];
    int s = 0;
    #pragma unroll
    for (int i = 0; i < 7; ++i) {
        int b = base + i;
        int v = (b < NBINS) ? counts[b] : 0;
        loc[i] = s;            // exclusive within this thread's chunk
        s += v;
    }
    buf[0][tid] = s;
    __syncthreads();
    int src = 0;
    for (int d = 1; d < 256; d <<= 1) {
        int x = buf[src][tid] + ((tid >= d) ? buf[src][tid - d] : 0);
        buf[src ^ 1][tid] = x;
        __syncthreads();
        src ^= 1;
    }
    int excl = (tid == 0) ? 0 : buf[src][tid - 1];
    #pragma unroll
    for (int i = 0; i < 7; ++i) {
        int b = base + i;
        if (b < NBINS) {
            offsets[b] = excl + loc[i];
            cursors[b] = excl + loc[i];
        }
    }
    if (tid == 255) offsets[NBINS] = buf[src][255];
}

__global__ __launch_bounds__(256) void ScatterNL_fill(
    const int* __restrict__ qinds, int Q, int* __restrict__ cursors,
    int* __restrict__ list)
{
    int stride = gridDim.x * blockDim.x;
    for (int q = blockIdx.x * blockDim.x + threadIdx.x; q < Q; q += stride) {
        int t = qinds[3*q], h = qinds[3*q+1], w = qinds[3*q+2];
        int b = (t * NBH + h / TILE) * NBW + w / TILE;
        int pos = atomicAdd(&cursors[b], 1);
        list[pos] = q;
    }
}

__global__ __launch_bounds__(256) void ScatterNL_accum(
    const float* __restrict__ vid, const float* __restrict__ patches,
    const int* __restrict__ qinds, const int* __restrict__ offsets,
    const int* __restrict__ list, float* __restrict__ out)
{
    __shared__ float acc[C_DIM * TILE * TILE];   // 17,328 B -> wave-limited occupancy

    int bid = blockIdx.x;
    int ts  = bid / (NBH * NBW);                 // output t-slice 0..9
    int r   = bid % (NBH * NBW);
    int bh  = r / NBW, bw = r % NBW;
    int h0  = bh * TILE, w0 = bw * TILE;
    int THe = min(TILE, H_DIM - h0);             // 38 (18 on last row)
    int TWe = min(TILE, W_DIM - w0);

    for (int i = threadIdx.x; i < C_DIM * TILE * TILE; i += blockDim.x)
        acc[i] = 0.f;
    __syncthreads();

    const int lane = threadIdx.x & 63;
    const int wv   = threadIdx.x >> 6;           // 0..3
    const int NW   = blockDim.x >> 6;            // 4 waves

    // Per-lane (c,i,j) for k = lane, lane+64, lane+128. Segments 0,1 fully
    // valid (k<=127<147); segment 2 valid for lane<19.
    int cc[3], ii[3], jj[3];
    #pragma unroll
    for (int s = 0; s < 3; ++s) {
        int k = lane + 64 * s;
        int kk = (k < HALF) ? k : 0;
        cc[s] = kk / 49;
        int rr = kk % 49;
        ii[s] = rr / 7;
        jj[s] = rr % 7;
    }
    const bool v2ok = (lane < HALF - 128);       // lane < 19

    for (int tb = ts - 1; tb <= ts; ++tb) {
        if (tb < 0 || tb > T_DIM - PT) continue;
        int dt = ts - tb;                        // which patch half lands in slice ts
        for (int sh = max(bh - 1, 0); sh <= bh; ++sh) {
            for (int sw = max(bw - 1, 0); sw <= bw; ++sw) {
                int bin   = (tb * NBH + sh) * NBW + sw;
                int start = offsets[bin], end = offsets[bin + 1];
                int nb    = (end - start + 63) >> 6;
                for (int bi = wv; bi < nb; bi += NW) {
                    int e = start + (bi << 6) + lane;
                    int q = 0, hw = 0;
                    bool inb = (e < end);
                    if (inb) {
                        q = list[e];                       // coalesced burst
                        int qh = qinds[3*q+1];             // L2-hot gather, 64-way MLP
                        int qw = qinds[3*q+2];
                        hw = (qh << 16) | qw;
                    }
                    int qh = hw >> 16, qw = hw & 0xffff;
                    bool ok = inb && (qh + PS > h0) && (qh < h0 + THe)
                                  && (qw + PS > w0) && (qw < w0 + TWe);
                    unsigned long long m = __ballot(ok);
                    while (m) {
                        int src = __ffsll((long long)m) - 1;
                        m &= m - 1;
                        int qs  = __shfl(q, src);
                        int hws = __shfl(hw, src);
                        int qhs = hws >> 16, qws = hws & 0xffff;
                        const float* base = patches + (size_t)qs * ELEM_PER_Q + dt * HALF;
                        float v0 = base[lane];
                        float v1 = base[lane + 64];
                        float v2 = v2ok ? base[lane + 128] : 0.f;
                        #pragma unroll
                        for (int s = 0; s < 3; ++s) {
                            float v = (s == 0) ? v0 : (s == 1) ? v1 : v2;
                            bool lv = (s < 2) || v2ok;
                            int hh = qhs + ii[s] - h0;
                            int ww = qws + jj[s] - w0;
                            if (lv && hh >= 0 && hh < THe && ww >= 0 && ww < TWe)
                                atomicAdd(&acc[(cc[s] * TILE + hh) * TILE + ww], v);
                        }
                    }
                }
            }
        }
    }
    __syncthreads();

    // Exclusive write-out: out = vid2fill + acc. Each output element written once.
    #pragma unroll
    for (int c = 0; c < C_DIM; ++c) {
        for (int y = wv; y < THe; y += NW) {
            if (lane < TWe) {
                size_t o = (((size_t)ts * C_DIM + c) * H_DIM + (h0 + y)) * W_DIM + w0 + lane;
                out[o] = vid[o] + acc[(c * TILE + y) * TILE + lane];
            }
        }
    }
}

extern "C" void kernel_launch(void* const* d_in, const int* in_sizes, int n_in,
                              void* d_out, int out_size, void* d_ws, size_t ws_size,
                              hipStream_t stream) {
    const float* vid     = (const float*)d_in[0];
    const float* patches = (const float*)d_in[1];
    const int*   qinds   = (const int*)d_in[2];
    float* out = (float*)d_out;
    int Q = in_sizes[2] / 3;

    int* ws      = (int*)d_ws;
    int* counts  = ws;
    int* offsets = ws + BINPAD;
    int* cursors = ws + 2 * BINPAD;
    int* list    = ws + 3 * BINPAD;

    hipMemsetAsync(counts, 0, BINPAD * sizeof(int), stream);  // ws is poisoned each call
    ScatterNL_hist<<<256, 256, 0, stream>>>(qinds, Q, counts);
    ScatterNL_scan<<<1, 256, 0, stream>>>(counts, offsets, cursors);
    ScatterNL_fill<<<256, 256, 0, stream>>>(qinds, Q, cursors, list);
    ScatterNL_accum<<<T_DIM * NBH * NBW, 256, 0, stream>>>(
        vid, patches, qinds, offsets, list, out);
}